// Round 6
// baseline (100.514 us; speedup 1.0000x reference)
//
#include <hip/hip_runtime.h>
#include <math.h>

// LMAX=3, NMAX=3, RC=6, UNIT=1.0, NSPEC=4, L=4
// c[s][n][a][b]: 256 floats; per-species comp k = n*16 + a*4 + b (64 comps)
constexpr int   NB    = 1024;         // accum blocks (4 per CU -> 8 waves/SIMD nominal)
constexpr int   BT    = 512;          // threads per block (8 waves)
constexpr int   WAVES = BT / 64;      // species = wid & 3 (2 cohorts/species/block)
constexpr int   COHORTS = NB * (WAVES / 4);  // 2048 cohorts per species
constexpr float RC    = 6.0f;

__device__ inline void global_fadd(float* p, float v) {
    unsafeAtomicAdd(p, v);            // HW global_atomic_add_f32, no return
}

// ---------------- kernel 0: zero the 256-float global accumulator ----------
__global__ __launch_bounds__(256) void soap_zero(float* __restrict__ c) {
    c[threadIdx.x] = 0.0f;
}

// ---------------- kernel 1: per-atom features, register accumulation -------
__global__ __launch_bounds__(BT) void soap_accum(const float* __restrict__ coo,
                                                 const int*   __restrict__ numbers,
                                                 float*       __restrict__ c_glob,
                                                 int n) {
    const int lane = threadIdx.x & 63;
    const int wid  = threadIdx.x >> 6;
    const int ws   = wid & 3;                              // this wave's species
    const int cohort = blockIdx.x * (WAVES / 4) + (wid >> 2);
    const int stride = COHORTS * 64;                       // 131072

    float acc[64];
    #pragma unroll
    for (int k = 0; k < 64; ++k) acc[k] = 0.0f;

    int i = cohort * 64 + lane;
    // prime the software pipeline (depth-1 prefetch)
    int   j0 = (i < n) ? i : 0;
    float x = coo[3 * j0 + 0];
    float y = coo[3 * j0 + 1];
    float z = coo[3 * j0 + 2];
    int   s = numbers[j0];

    for (; i < n; ) {
        const int inext = i + stride;
        const int jn = (inext < n) ? inext : (n - 1);      // clamped prefetch
        const float xn = coo[3 * jn + 0];
        const float yn = coo[3 * jn + 1];
        const float zn = coo[3 * jn + 2];
        const int   sn = numbers[jn];

        const float r2 = x * x + y * y + z * z;
        const float d  = sqrtf(r2);
        float t = 1.0f - d * (1.0f / RC);
        t = fmaxf(t, 0.0f);                                // cutoff -> 0 outside RC
        float r = __expf(-0.5f * r2) * t * t;
        r = (s == ws) ? r : 0.0f;                          // species mask, branchless

        // ---- regular solid harmonics on the (4,4) grid ----
        float Y[16];
        Y[0]  = 1.0f;                                      // (0,0)
        const float Re11 = 0.5f * x, Im11 = 0.5f * y, Re10 = z;
        Y[5]  = Re10;
        Y[4]  = Re11;
        Y[1]  = Im11;
        const float Re22 = 0.25f * (x * Re11 - y * Im11);
        const float Im22 = 0.25f * (x * Im11 + y * Re11);
        const float Re21 = z * Re11, Im21 = z * Im11;
        const float Re20 = 0.25f * (3.0f * z * Re10 - r2);
        Y[10] = Re20;
        Y[9]  = Re21;
        Y[6]  = Im21;
        Y[8]  = Re22;
        Y[2]  = Im22;
        const float Re33 = (x * Re22 - y * Im22) * (1.0f / 6.0f);
        const float Im33 = (x * Im22 + y * Re22) * (1.0f / 6.0f);
        const float Re32 = z * Re22, Im32 = z * Im22;
        const float Re30 = (5.0f * z * Re20 - r2 * Re10) * (1.0f / 9.0f);
        const float Re31 = (5.0f * z * Re21 - r2 * Re11) * (1.0f / 8.0f);
        const float Im31 = (5.0f * z * Im21 - r2 * Im11) * (1.0f / 8.0f);
        Y[15] = Re30;
        Y[14] = Re31;
        Y[11] = Im31;
        Y[13] = Re32;
        Y[7]  = Im32;
        Y[12] = Re33;
        Y[3]  = Im33;

        const float f0 = r;
        const float f1 = f0 * r2;
        const float f2 = f1 * r2;
        const float f3 = f2 * r2;

        #pragma unroll
        for (int q = 0; q < 16; ++q) {
            acc[ 0 + q] += f0 * Y[q];
            acc[16 + q] += f1 * Y[q];
            acc[32 + q] += f2 * Y[q];
            acc[48 + q] += f3 * Y[q];
        }

        x = xn; y = yn; z = zn; s = sn;
        i = inext;
    }

    // ---- block reduction: LDS transpose, no per-atom atomics ----
    __shared__ float sh[64][65];        // one wave's 64 lanes x 64 comps, padded
    __shared__ float sh2[8][64];
    __shared__ float blockpart[256];    // [species][comp]

    for (int w = 0; w < WAVES; ++w) {
        __syncthreads();
        if (wid == w) {
            #pragma unroll
            for (int k = 0; k < 64; ++k) sh[lane][k] = acc[k];
        }
        __syncthreads();
        float p = 0.0f;
        #pragma unroll
        for (int rr = 0; rr < 8; ++rr) p += sh[wid * 8 + rr][lane];
        sh2[wid][lane] = p;
        __syncthreads();
        if (threadIdx.x < 64) {
            float q = 0.0f;
            #pragma unroll
            for (int g = 0; g < 8; ++g) q += sh2[g][threadIdx.x];
            const int sw = w & 3;
            if (w < 4) blockpart[sw * 64 + threadIdx.x] = q;
            else       blockpart[sw * 64 + threadIdx.x] += q;
        }
    }
    __syncthreads();
    // one global atomic per component per block (256 per block)
    if (threadIdx.x < 256)
        global_fadd(&c_glob[threadIdx.x], blockpart[threadIdx.x]);
}

// ---------------- kernel 2: bilinear contraction + normalize ---------------
__global__ __launch_bounds__(1024) void soap_finish(const float* __restrict__ c_glob,
                                                    float* __restrict__ out) {
    __shared__ float c[256];
    __shared__ float red[16];
    __shared__ float snorm;
    const int t = threadIdx.x;
    if (t < 256) c[t] = c_glob[t];
    __syncthreads();

    // p index (i,j,k,n,x), t = i*256 + j*64 + k*16 + n*4 + x
    const int x  = t & 3;
    const int nn = (t >> 2) & 3;
    const int kk = (t >> 4) & 3;
    const int j  = (t >> 6) & 3;
    const int i  = (t >> 8) & 3;

    float p1 = 0.0f, p2 = 0.0f;
    #pragma unroll
    for (int b = 0; b < 4; ++b) {
        const float yr = (x > b) ? 2.0f : ((x == b) ? 1.0f : 0.0f);
        p1 += yr * c[((j * 4 + nn) * 4 + x) * 4 + b] * c[((i * 4 + kk) * 4 + x) * 4 + b];
    }
    #pragma unroll
    for (int a = 0; a < 4; ++a) {
        const float yi = (x > a) ? 2.0f : 0.0f;
        p2 += yi * c[((j * 4 + nn) * 4 + a) * 4 + x] * c[((i * 4 + kk) * 4 + a) * 4 + x];
    }

    const double fact[8] = {1, 1, 2, 6, 24, 120, 720, 5040};
    const double ak = 1.0 / ((2 * x + 1) * exp2((double)(2 * kk + x)) * fact[kk] * fact[kk + x]);
    const double an = 1.0 / ((2 * x + 1) * exp2((double)(2 * nn + x)) * fact[nn] * fact[nn + x]);
    const float val = (p1 + p2) * (float)sqrt(ak * an);

    float sq = val * val;
    #pragma unroll
    for (int off = 32; off > 0; off >>= 1) sq += __shfl_down(sq, off, 64);
    if ((t & 63) == 0) red[t >> 6] = sq;
    __syncthreads();
    if (t == 0) {
        float ssum = 0.0f;
        #pragma unroll
        for (int w = 0; w < 16; ++w) ssum += red[w];
        snorm = sqrtf(ssum);
    }
    __syncthreads();

    out[t] = val / (snorm + 1.1920929e-07f);
}

// ---------------- launch ----------------
extern "C" void kernel_launch(void* const* d_in, const int* in_sizes, int n_in,
                              void* d_out, int out_size, void* d_ws, size_t ws_size,
                              hipStream_t stream) {
    const float* coo     = (const float*)d_in[0];
    const int*   numbers = (const int*)d_in[1];
    const int    n       = in_sizes[1];
    float*       c_glob  = (float*)d_ws;     // 256-float global accumulator
    float*       out     = (float*)d_out;

    soap_zero  <<<1,   256, 0, stream>>>(c_glob);
    soap_accum <<<NB,  BT,  0, stream>>>(coo, numbers, c_glob, n);
    soap_finish<<<1,  1024, 0, stream>>>(c_glob, out);
}

// Round 11
// 84.755 us; speedup vs baseline: 1.1859x; 1.1859x over previous
//
#include <hip/hip_runtime.h>
#include <math.h>

// LMAX=3, NMAX=3, RC=6, UNIT=1.0, NSPEC=4, L=4
// c[s][n][a][b]: 256 floats; per-species comp k = n*16 + a*4 + b (64 comps)
constexpr int   NB   = 1024;          // accum blocks
constexpr int   BT   = 256;           // 4 waves per block; wave id == species
constexpr int   NREP = 8;             // c_glob replicas (atomic chain depth 1024->128)
constexpr float RC   = 6.0f;

__device__ inline void global_fadd(float* p, float v) {
    unsafeAtomicAdd(p, v);            // HW global_atomic_add_f32, no return
}

// ---------------- kernel 0: zero the replicated global accumulator --------
__global__ __launch_bounds__(256) void soap_zero(float* __restrict__ c) {
    c[blockIdx.x * 256 + threadIdx.x] = 0.0f;      // <<<NREP, 256>>>
}

// ---------------- kernel 1: per-atom features, register accumulation -------
// No LDS, no spill risk: acc[64] + ~35 temps, VGPR cap 128 via launch_bounds.
__global__ __launch_bounds__(BT, 4) void soap_accum(const float* __restrict__ coo,
                                                    const int*   __restrict__ numbers,
                                                    float*       __restrict__ c_glob,
                                                    int n) {
    const int lane = threadIdx.x & 63;
    const int ws   = threadIdx.x >> 6;             // wave id == species (0..3)
    const int stride = NB * 64;                    // 65536

    float acc[64];
    #pragma unroll
    for (int k = 0; k < 64; ++k) acc[k] = 0.0f;

    int i = blockIdx.x * 64 + lane;
    int j0 = (i < n) ? i : 0;                      // prime depth-1 prefetch
    float x = coo[3 * j0 + 0];
    float y = coo[3 * j0 + 1];
    float z = coo[3 * j0 + 2];
    int   s = numbers[j0];

    while (i < n) {
        const int inext = i + stride;
        const int jn = (inext < n) ? inext : 0;    // clamped prefetch
        const float xn = coo[3 * jn + 0];
        const float yn = coo[3 * jn + 1];
        const float zn = coo[3 * jn + 2];
        const int   sn = numbers[jn];

        const float r2 = x * x + y * y + z * z;
        const float dd = sqrtf(r2);
        float t = fmaxf(1.0f - dd * (1.0f / RC), 0.0f);   // cutoff, branchless
        float f0 = __expf(-0.5f * r2) * t * t;
        f0 = (s == ws) ? f0 : 0.0f;                       // species mask
        const float f1 = f0 * r2;
        const float f2 = f1 * r2;
        const float f3 = f2 * r2;

        // grid[l, l-m]=Re, grid[l-m, l]=Im; q = row*4+col; fmac immediately
        #define ACC4(q, val) do { const float yv_ = (val);          \
            acc[(q)]      = fmaf(f0, yv_, acc[(q)]);                \
            acc[16 + (q)] = fmaf(f1, yv_, acc[16 + (q)]);           \
            acc[32 + (q)] = fmaf(f2, yv_, acc[32 + (q)]);           \
            acc[48 + (q)] = fmaf(f3, yv_, acc[48 + (q)]); } while (0)

        // l = 0 : Y = 1
        acc[0] += f0; acc[16] += f1; acc[32] += f2; acc[48] += f3;
        // l = 1
        const float Re11 = 0.5f * x, Im11 = 0.5f * y, Re10 = z;
        ACC4(5, Re10); ACC4(4, Re11); ACC4(1, Im11);
        // l = 2
        const float Re22 = 0.25f * (x * Re11 - y * Im11);
        const float Im22 = 0.25f * (x * Im11 + y * Re11);
        const float Re21 = z * Re11, Im21 = z * Im11;
        const float Re20 = 0.25f * (3.0f * z * Re10 - r2);
        ACC4(10, Re20); ACC4(9, Re21); ACC4(6, Im21); ACC4(8, Re22); ACC4(2, Im22);
        // l = 3
        const float Re33 = (x * Re22 - y * Im22) * (1.0f / 6.0f);
        const float Im33 = (x * Im22 + y * Re22) * (1.0f / 6.0f);
        const float Re32 = z * Re22, Im32 = z * Im22;
        const float Re30 = (5.0f * z * Re20 - r2 * Re10) * (1.0f / 9.0f);
        const float Re31 = (5.0f * z * Re21 - r2 * Re11) * (1.0f / 8.0f);
        const float Im31 = (5.0f * z * Im21 - r2 * Im11) * (1.0f / 8.0f);
        ACC4(15, Re30); ACC4(14, Re31); ACC4(11, Im31); ACC4(13, Re32);
        ACC4(7, Im32); ACC4(12, Re33); ACC4(3, Im33);
        #undef ACC4

        x = xn; y = yn; z = zn; s = sn;
        i = inext;
    }

    // ---- in-register wave reduction: bisection over lanes ----
    // After 6 stages, lane k holds the wave-total of component k.
    // hi-lanes keep the UPPER half each stage -> lane's bits select comp bits.
    #pragma unroll
    for (int m = 32; m >= 1; m >>= 1) {
        const bool hi = (lane & m) != 0;
        #pragma unroll
        for (int q = 0; q < m; ++q) {
            const float give = hi ? acc[q] : acc[q + m];
            const float keep = hi ? acc[q + m] : acc[q];
            acc[q] = keep + __shfl_xor(give, m, 64);
        }
    }
    // one atomic per thread into this block's replica
    global_fadd(&c_glob[(blockIdx.x & (NREP - 1)) * 256 + ws * 64 + lane], acc[0]);
}

// ---------------- kernel 2: bilinear contraction + normalize ---------------
__global__ __launch_bounds__(1024) void soap_finish(const float* __restrict__ c_glob,
                                                    float* __restrict__ out) {
    __shared__ float c[256];
    __shared__ float red[16];
    __shared__ float snorm;
    const int t = threadIdx.x;
    if (t < 256) {
        float s = 0.0f;
        #pragma unroll
        for (int rep = 0; rep < NREP; ++rep) s += c_glob[rep * 256 + t];
        c[t] = s;
    }
    __syncthreads();

    // p index (i,j,k,n,x), t = i*256 + j*64 + k*16 + n*4 + x
    const int x  = t & 3;
    const int nn = (t >> 2) & 3;
    const int kk = (t >> 4) & 3;
    const int j  = (t >> 6) & 3;
    const int i  = (t >> 8) & 3;

    float p1 = 0.0f, p2 = 0.0f;
    #pragma unroll
    for (int b = 0; b < 4; ++b) {
        const float yr = (x > b) ? 2.0f : ((x == b) ? 1.0f : 0.0f);
        p1 += yr * c[((j * 4 + nn) * 4 + x) * 4 + b] * c[((i * 4 + kk) * 4 + x) * 4 + b];
    }
    #pragma unroll
    for (int a = 0; a < 4; ++a) {
        const float yi = (x > a) ? 2.0f : 0.0f;
        p2 += yi * c[((j * 4 + nn) * 4 + a) * 4 + x] * c[((i * 4 + kk) * 4 + a) * 4 + x];
    }

    const double fact[8] = {1, 1, 2, 6, 24, 120, 720, 5040};
    const double ak = 1.0 / ((2 * x + 1) * exp2((double)(2 * kk + x)) * fact[kk] * fact[kk + x]);
    const double an = 1.0 / ((2 * x + 1) * exp2((double)(2 * nn + x)) * fact[nn] * fact[nn + x]);
    const float val = (p1 + p2) * (float)sqrt(ak * an);

    float sq = val * val;
    #pragma unroll
    for (int off = 32; off > 0; off >>= 1) sq += __shfl_down(sq, off, 64);
    if ((t & 63) == 0) red[t >> 6] = sq;
    __syncthreads();
    if (t == 0) {
        float ssum = 0.0f;
        #pragma unroll
        for (int w = 0; w < 16; ++w) ssum += red[w];
        snorm = sqrtf(ssum);
    }
    __syncthreads();

    out[t] = val / (snorm + 1.1920929e-07f);
}

// ---------------- launch ----------------
extern "C" void kernel_launch(void* const* d_in, const int* in_sizes, int n_in,
                              void* d_out, int out_size, void* d_ws, size_t ws_size,
                              hipStream_t stream) {
    const float* coo     = (const float*)d_in[0];
    const int*   numbers = (const int*)d_in[1];
    const int    n       = in_sizes[1];
    float*       c_glob  = (float*)d_ws;     // NREP*256 floats
    float*       out     = (float*)d_out;

    soap_zero  <<<NREP, 256, 0, stream>>>(c_glob);
    soap_accum <<<NB,   BT,  0, stream>>>(coo, numbers, c_glob, n);
    soap_finish<<<1,   1024, 0, stream>>>(c_glob, out);
}